// Round 8
// baseline (293.407 us; speedup 1.0000x reference)
//
#include <hip/hip_runtime.h>
#include <hip/hip_bf16.h>
#include <stdint.h>

// ---------------------------------------------------------------------------
// Self-attention, B=4 S=2048 D=1024, fp32 in/out, fp16 MFMA compute.
// R8 = R6 shape (512 thr, BM=256, 16x16x32 MFMA, 64x64 wave tiles) +
// single-barrier ping-pong LDS double-buffer, BK=32:
//   stage(0)->buf0; loop: barrier; stage(i+1)->other; mfma(buf cur); swap.
// The barrier drain (vmcnt 0) for iter i+1 now overlaps MFMA(i) — attacks
// the ~50% idle R6 showed (MfmaUtil 33% vs ~70% LDS-bound ceiling).
// Swizzle (4 slots/row): phys = chunk ^ ((row>>1)&3) -> exactly 2-way bank
// aliasing on frag ds_read_b128 (free, m136).
//   0) cvt: x,w -> fp16 (one dispatch)
//   1) proj z=3: q,k fp16 row-major; z==2 -> vt[b][d][s] via LDS transpose
//   2) scores fp16 (z=batch)  3) softmax in place  4) out fp32
// bm-fastest grid: same-XCD blocks share the A panel (R4: FETCH 150->42 MB).
// ---------------------------------------------------------------------------

typedef __attribute__((ext_vector_type(8))) _Float16 f16x8;
typedef __attribute__((ext_vector_type(4))) float f32x4;
typedef __attribute__((ext_vector_type(4))) unsigned short u16x4;

__device__ inline unsigned short f2h(float f) {
    union { _Float16 h; unsigned short u; } x;
    x.h = (_Float16)f;   // RNE
    return x.u;
}
__device__ inline float h2f(unsigned short u) {
    union { unsigned short u; _Float16 h; } x;
    x.u = u;
    return (float)x.h;
}

__device__ inline void async16(const unsigned short* g, unsigned short* l) {
    __builtin_amdgcn_global_load_lds(
        (__attribute__((address_space(1))) void*)g,
        (__attribute__((address_space(3))) void*)l, 16, 0, 0);
}

// MODE 0: proj (BN=128): z<2 -> fp16 row-major into C (+z*sCz);
//         z==2 -> vt transpose into C2 (vt[b][d][s], ld 2048, bstride 2^21).
// MODE 1: fp16 row-major into C (scores).
// MODE 2: fp32 row-major into C (final out).
// Tile: BM=256 x BN, BK=32, dbuf. 8 waves: wr=wave>>1 (4), wc=wave&1 (2).
template <int MODE, int BN>
__global__ __launch_bounds__(512)
void gemm512(const unsigned short* __restrict__ A,
             const unsigned short* __restrict__ B,
             void* __restrict__ C, void* __restrict__ C2,
             int K, int ldA, int ldB, int ldC,
             long sAz, long sBz, long sCz)
{
    constexpr int NT  = BN / 32;            // MFMA col-tiles per wave
    constexpr int BCH = BN * 4;             // B chunks (16B) per buffer
    constexpr int BUF = (256 + BN) * 32;    // halves per buffer
    __shared__ __align__(16) unsigned short smem[2 * BUF];

    const int tid  = threadIdx.x;
    const int lane = tid & 63;
    const int wave = tid >> 6;
    const int wr   = wave >> 1, wc = wave & 1;
    const int quad = lane >> 4, lrow = lane & 15;
    const int bm   = blockIdx.x, bn = blockIdx.y, z = blockIdx.z;  // bm fastest

    const unsigned short* Az = A + (long)z * sAz;
    const unsigned short* Bz = B + (long)z * sBz;

    // staging: rows x 4 slots of 16B; slot s of row r holds logical k-chunk
    // s ^ ((r>>1)&3). A: 1024 chunks = 2/thread; B: BCH chunks.
    const int rA0 = tid >> 2,          cA0 = (tid & 3) ^ ((rA0 >> 1) & 3);
    const int rA1 = (tid + 512) >> 2,  cA1 = (tid & 3) ^ ((rA1 >> 1) & 3);
    const unsigned short* gA0 = Az + (long)(bm * 256 + rA0) * ldA + cA0 * 8;
    const unsigned short* gA1 = Az + (long)(bm * 256 + rA1) * ldA + cA1 * 8;
    const int rB0 = tid >> 2,          cB0 = (tid & 3) ^ ((rB0 >> 1) & 3);
    const unsigned short* gB0 = (tid < BCH)
        ? Bz + (long)(bn * BN + rB0) * ldB + cB0 * 8 : nullptr;

    f32x4 acc[4][NT];
#pragma unroll
    for (int i = 0; i < 4; ++i)
#pragma unroll
        for (int j = 0; j < NT; ++j)
            acc[i][j] = f32x4{0.f, 0.f, 0.f, 0.f};

    const int pc = (quad ^ ((lrow >> 1) & 3)) * 8;   // frag de-swizzle (invariant)

    auto stage = [&](int b) {
        unsigned short* As = smem + b * BUF;
        unsigned short* Bs = As + 256 * 32;
        async16(gA0, &As[tid * 8]);
        async16(gA1, &As[(tid + 512) * 8]);
        if (BCH == 512) {
            async16(gB0, &Bs[tid * 8]);
        } else if (tid < BCH) {
            async16(gB0, &Bs[tid * 8]);
        }
        gA0 += 32; gA1 += 32;
        if (BCH == 512 || tid < BCH) gB0 += 32;
    };
    auto compute = [&](int b) {
        const unsigned short* As = smem + b * BUF;
        const unsigned short* Bs = As + 256 * 32;
        f16x8 af[4], bf[NT];
#pragma unroll
        for (int mt = 0; mt < 4; ++mt)
            af[mt] = *(const f16x8*)&As[(wr * 64 + mt * 16 + lrow) * 32 + pc];
#pragma unroll
        for (int nt = 0; nt < NT; ++nt)
            bf[nt] = *(const f16x8*)&Bs[(wc * (BN / 2) + nt * 16 + lrow) * 32 + pc];
#pragma unroll
        for (int mt = 0; mt < 4; ++mt)
#pragma unroll
            for (int nt = 0; nt < NT; ++nt)
                acc[mt][nt] = __builtin_amdgcn_mfma_f32_16x16x32_f16(
                    af[mt], bf[nt], acc[mt][nt], 0, 0, 0);
    };

    const int niter = K >> 5;        // even for all our shapes (32 or 64)
    stage(0);
    for (int i = 0; i < niter; i += 2) {
        __syncthreads();             // drains loads for buf0 (iter i)
        if (i + 1 < niter) stage(1); // prefetch iter i+1 during compute(i)
        compute(0);
        __syncthreads();             // drains loads for buf1 (iter i+1)
        if (i + 2 < niter) stage(0); // prefetch iter i+2 during compute(i+1)
        compute(1);
    }

    const int col_base = bn * BN + wc * (BN / 2);

    if (MODE != 0 || z < 2) {
        const int row_base = bm * 256 + wr * 64;
        const long zC = (long)z * sCz;
#pragma unroll
        for (int mt = 0; mt < 4; ++mt)
#pragma unroll
            for (int nt = 0; nt < NT; ++nt)
#pragma unroll
                for (int r = 0; r < 4; ++r) {
                    const int row = row_base + mt * 16 + quad * 4 + r;
                    const int col = col_base + nt * 16 + lrow;
                    if (MODE == 2)
                        ((float*)C)[zC + (long)row * ldC + col] = acc[mt][nt][r];
                    else
                        ((unsigned short*)C)[zC + (long)row * ldC + col] =
                            f2h(acc[mt][nt][r]);
                }
    } else {
        // vt transpose (BN=128): 4 phases of 64 token-rows. T[col 128][row 64]
        // pitch 72 halves (144B rows keep 16B align); aliases smem after the
        // leading barrier of each phase.
        unsigned short* T = smem;   // 128*72 = 9216 halves <= 2*BUF
#pragma unroll
        for (int p = 0; p < 4; ++p) {
            __syncthreads();
            if (wr == p) {
#pragma unroll
                for (int mt = 0; mt < 4; ++mt)
#pragma unroll
                    for (int nt = 0; nt < NT; ++nt) {
                        const int row_l = mt * 16 + quad * 4;     // within band
                        const int col_l = wc * 64 + nt * 16 + lrow;
                        u16x4 pk = {f2h(acc[mt][nt][0]), f2h(acc[mt][nt][1]),
                                    f2h(acc[mt][nt][2]), f2h(acc[mt][nt][3])};
                        *(u16x4*)&T[col_l * 72 + row_l] = pk;
                    }
            }
            __syncthreads();
            // copy out: 128 cols x 64 rows = 8192 halves = 512 thr x 16
            const int c  = tid >> 2;
            const int j0 = (tid & 3) * 16;
            const int tok0 = bm * 256 + p * 64;   // tile never crosses batch
            const int bb = tok0 >> 11;            // (2048 % 256 == 0)
            const int s0 = (tok0 & 2047) + j0;
            unsigned short* dst = (unsigned short*)C2 + (long)bb * 2097152 +
                                  (long)(bn * 128 + c) * 2048 + s0;
            const unsigned short* srcT = &T[c * 72 + j0];
            *(f16x8*)dst = *(const f16x8*)srcT;
            *(f16x8*)(dst + 8) = *(const f16x8*)(srcT + 8);
        }
    }
}

// fused fp32 -> fp16 conversion: blocks [0,4096) -> x, [4096,5632) -> weights
__global__ __launch_bounds__(256)
void cvt_all(const float* __restrict__ x, const float* __restrict__ w0,
             const float* __restrict__ w1, const float* __restrict__ w2,
             unsigned short* __restrict__ xh, unsigned short* __restrict__ wh)
{
    const int bid = blockIdx.x;
    const float* s;
    unsigned short* d;
    long i;
    if (bid < 4096) {
        s = x; d = xh;
        i = ((long)bid * 256 + threadIdx.x) * 8;
    } else {
        const int wid = bid - 4096;          // [0,1536)
        const int w = wid >> 9;              // weight index
        s = (w == 0) ? w0 : (w == 1) ? w1 : w2;
        d = wh + (long)w * 1048576;
        i = ((long)(wid & 511) * 256 + threadIdx.x) * 8;
    }
    f32x4 a = *(const f32x4*)(s + i);
    f32x4 b = *(const f32x4*)(s + i + 4);
    union { unsigned short u[8]; f16x8 v; } t;
#pragma unroll
    for (int j = 0; j < 4; ++j) { t.u[j] = f2h(a[j]); t.u[4 + j] = f2h(b[j]); }
    *(f16x8*)(d + i) = t.v;
}

// in-place fp16 row softmax: row = 2048 fp16, one block per row.
__global__ __launch_bounds__(256)
void softmax16(unsigned short* __restrict__ sc)
{
    const long row = blockIdx.x;
    unsigned short* srow = sc + row * 2048;
    const int tid = threadIdx.x;

    union { u16x4 p[2]; unsigned short u[8]; } in;
    in.p[0] = *(const u16x4*)(srow + tid * 8);
    in.p[1] = *(const u16x4*)(srow + tid * 8 + 4);
    float v[8];
#pragma unroll
    for (int i = 0; i < 8; ++i) v[i] = h2f(in.u[i]);

    float m = v[0];
#pragma unroll
    for (int i = 1; i < 8; ++i) m = fmaxf(m, v[i]);
#pragma unroll
    for (int off = 32; off; off >>= 1) m = fmaxf(m, __shfl_xor(m, off));

    __shared__ float redm[4], reds[4];
    if ((tid & 63) == 0) redm[tid >> 6] = m;
    __syncthreads();
    m = fmaxf(fmaxf(redm[0], redm[1]), fmaxf(redm[2], redm[3]));

    float s = 0.f;
#pragma unroll
    for (int i = 0; i < 8; ++i) { v[i] = __expf(v[i] - m); s += v[i]; }
#pragma unroll
    for (int off = 32; off; off >>= 1) s += __shfl_xor(s, off);
    if ((tid & 63) == 0) reds[tid >> 6] = s;
    __syncthreads();
    s = reds[0] + reds[1] + reds[2] + reds[3];

    const float inv = 1.f / s;
    union { unsigned short u[8]; f16x8 w; } t;
#pragma unroll
    for (int i = 0; i < 8; ++i) t.u[i] = f2h(v[i] * inv);
    *(f16x8*)(srow + tid * 8) = t.w;
}

extern "C" void kernel_launch(void* const* d_in, const int* in_sizes, int n_in,
                              void* d_out, int out_size, void* d_ws, size_t ws_size,
                              hipStream_t stream)
{
    const float* x  = (const float*)d_in[0];
    const float* wq = (const float*)d_in[1];
    const float* wk = (const float*)d_in[2];
    const float* wv = (const float*)d_in[3];
    float* out = (float*)d_out;

    // batched: [sc fp16 33.5MB (aliases xh 16.8 | wh 6.3)] [q][k][vt] = 83.9MB
    // looped:  [xh|wh 23.1MB (per-batch sc fp16 8.4MB aliases xh)][q][k][vt]
    char* base = (char*)d_ws;
    const bool batched = (ws_size >= 88080384UL);   // 84 MB

    unsigned short* xh = (unsigned short*)base;
    unsigned short* wh = (unsigned short*)(base + 16777216);
    unsigned short* sc = (unsigned short*)base;
    unsigned short* q  = (unsigned short*)(base + (batched ? 33554432 : 23068672));
    unsigned short* k  = q + 8388608;
    unsigned short* vt = k + 8388608;

    // 0) conversions (single dispatch)
    cvt_all<<<5632, 256, 0, stream>>>(x, wq, wk, wv, xh, wh);

    // 1) fused projections: M=8192 N=1024 K=1024; z=0,1 -> q,k; z=2 -> vt
    //    grid (32,8,3) = 768 blocks = 3/CU (48 KB LDS)
    gemm512<0, 128><<<dim3(32, 8, 3), 512, 0, stream>>>(
        xh, wh, q, vt, 1024, 1024, 1024, 1024, 0L, 1048576L, 8388608L);

    if (batched) {
        // 2) scores fp16: M=N=2048 K=1024, z=batch; (8,16,4)=512 blocks
        gemm512<1, 128><<<dim3(8, 16, 4), 512, 0, stream>>>(
            q, k, sc, nullptr, 1024, 1024, 1024, 2048,
            2097152L, 2097152L, 4194304L);
        // 3) softmax in place (8192 rows, fp16->fp16)
        softmax16<<<8192, 256, 0, stream>>>(sc);
        // 4) out: M=2048 N=1024 K=2048; 256x64 tiles, (8,16,4)=512 blocks
        gemm512<2, 64><<<dim3(8, 16, 4), 512, 0, stream>>>(
            sc, vt, out, nullptr, 2048, 2048, 2048, 1024,
            4194304L, 2097152L, 2097152L);
    } else {
        for (int b = 0; b < 4; ++b) {
            gemm512<1, 128><<<dim3(8, 16, 1), 512, 0, stream>>>(
                q + (long)b * 2097152, k + (long)b * 2097152, sc, nullptr,
                1024, 1024, 1024, 2048, 0L, 0L, 0L);
            softmax16<<<2048, 256, 0, stream>>>(sc);
            gemm512<2, 64><<<dim3(8, 16, 1), 512, 0, stream>>>(
                sc, vt + (long)b * 2097152, out + (long)b * 2097152, nullptr,
                2048, 2048, 2048, 1024, 0L, 0L, 0L);
        }
    }
}